// Round 5
// baseline (863.002 us; speedup 1.0000x reference)
//
#include <hip/hip_runtime.h>

// Problem constants (fixed by setup_inputs)
constexpr int B   = 16;
constexpr int N   = 16384;
constexpr int M   = 256;   // n_centers
constexpr int K   = 32;    // knn
constexpr int EMB = 256;

// Exact (non-contracted) squared distance in the reference's association
// order: ((dx*dx + dy*dy) + dz*dz). Must be bit-identical to XLA CPU so the
// FPS argmax / kNN top-k selections match.
__device__ __forceinline__ float sqdist(float px, float py, float pz,
                                        float cx, float cy, float cz) {
  float dx = __fsub_rn(px, cx);
  float dy = __fsub_rn(py, cy);
  float dz = __fsub_rn(pz, cz);
  return __fadd_rn(__fadd_rn(__fmul_rn(dx, dx), __fmul_rn(dy, dy)),
                   __fmul_rn(dz, dz));
}

// ---------------------------------------------------------------- FPS ------
constexpr int FPS_T = 1024;
constexpr int PPT = N / FPS_T;  // 16 points per thread

__global__ __launch_bounds__(FPS_T) void fps_kernel(
    const float* __restrict__ xyz, float* __restrict__ centers) {
  const int b = blockIdx.x;
  const int tid = threadIdx.x;
  const float* base = xyz + (size_t)b * N * 3;

  float px[PPT], py[PPT], pz[PPT], dist[PPT];
#pragma unroll
  for (int j = 0; j < PPT; ++j) {
    int n = tid + j * FPS_T;
    px[j] = base[n * 3 + 0];
    py[j] = base[n * 3 + 1];
    pz[j] = base[n * 3 + 2];
    dist[j] = __builtin_inff();
  }

  __shared__ float s_c[3];
  __shared__ float s_wv[FPS_T / 64];
  __shared__ int s_wi[FPS_T / 64];
  if (tid == 0) { s_c[0] = base[0]; s_c[1] = base[1]; s_c[2] = base[2]; }
  __syncthreads();

  for (int it = 0; it < M; ++it) {
    const float cx = s_c[0], cy = s_c[1], cz = s_c[2];
    if (tid == 0) {  // record current farthest (== scan's emitted carry)
      float* co = centers + ((size_t)b * M + it) * 3;
      co[0] = cx; co[1] = cy; co[2] = cz;
    }
    float bv = -1.0f;
    int bi = 0x7FFFFFFF;
#pragma unroll
    for (int j = 0; j < PPT; ++j) {
      float d = sqdist(px[j], py[j], pz[j], cx, cy, cz);
      float nd = fminf(dist[j], d);
      dist[j] = nd;
      if (nd > bv) { bv = nd; bi = tid + j * FPS_T; }  // strict > : first idx wins
    }
    // wave-level argmax (tie -> smaller index)
#pragma unroll
    for (int mm = 32; mm >= 1; mm >>= 1) {
      float ov = __shfl_xor(bv, mm, 64);
      int oi = __shfl_xor(bi, mm, 64);
      if (ov > bv || (ov == bv && oi < bi)) { bv = ov; bi = oi; }
    }
    if ((tid & 63) == 0) { s_wv[tid >> 6] = bv; s_wi[tid >> 6] = bi; }
    __syncthreads();
    if (tid < 64) {
      float v = (tid < FPS_T / 64) ? s_wv[tid] : -1.0f;
      int i = (tid < FPS_T / 64) ? s_wi[tid] : 0x7FFFFFFF;
#pragma unroll
      for (int mm = 32; mm >= 1; mm >>= 1) {
        float ov = __shfl_xor(v, mm, 64);
        int oi = __shfl_xor(i, mm, 64);
        if (ov > v || (ov == v && oi < i)) { v = ov; i = oi; }
      }
      if (tid == 0) {
        s_c[0] = base[(size_t)i * 3 + 0];
        s_c[1] = base[(size_t)i * 3 + 1];
        s_c[2] = base[(size_t)i * 3 + 2];
      }
    }
    __syncthreads();
  }
}

// ---------------------------------------------------------------- kNN ------
// Bucket-select on float bit prefixes (monotone for d >= 0). Only the SET of
// 32 nearest matters (max-pool later), so slots are written in arbitrary
// order; boundary-bucket ties resolved exactly by (bits, index).
constexpr int KT = 256;
constexpr int CAP = 512;
constexpr int NBUCKET = 1024;

__global__ __launch_bounds__(KT) void knn_kernel(
    const float* __restrict__ xyz, const float* __restrict__ centers,
    float* __restrict__ patches) {
  const int blk = blockIdx.x;      // b*M + m
  const int b = blk >> 8;          // M == 256
  const int tid = threadIdx.x;
  const float* base = xyz + (size_t)b * N * 3;

  __shared__ int hist[NBUCKET];
  __shared__ unsigned cb[CAP];
  __shared__ int ci[CAP];
  __shared__ int s_nin, s_ncand, s_tb;
  __shared__ int s_wsum[KT / 64];
  __shared__ float s_cc[3];

  if (tid == 0) {
    const float* c = centers + (size_t)blk * 3;
    s_cc[0] = c[0]; s_cc[1] = c[1]; s_cc[2] = c[2];
    s_nin = 0; s_ncand = 0;
  }
  for (int i = tid; i < NBUCKET; i += KT) hist[i] = 0;
  __syncthreads();

  const float cx = s_cc[0], cy = s_cc[1], cz = s_cc[2];

  // pass 1: histogram of 10-bit float prefixes
  for (int n = tid; n < N; n += KT) {
    float d = sqdist(base[n * 3], base[n * 3 + 1], base[n * 3 + 2], cx, cy, cz);
    atomicAdd(&hist[__float_as_uint(d) >> 21], 1);
  }
  __syncthreads();

  // block scan over 1024 buckets (4 per thread) to find threshold bucket
  int h0[4];
  int loc = 0;
#pragma unroll
  for (int i = 0; i < 4; ++i) { h0[i] = hist[tid * 4 + i]; loc += h0[i]; }
  int lane = tid & 63, wid = tid >> 6;
  int scan = loc;
  for (int off = 1; off < 64; off <<= 1) {
    int o = __shfl_up(scan, off, 64);
    if (lane >= off) scan += o;
  }
  if (lane == 63) s_wsum[wid] = scan;
  __syncthreads();
  int woff = 0;
  for (int w = 0; w < wid; ++w) woff += s_wsum[w];
  int c0 = woff + scan - loc;  // count strictly below this thread's buckets
#pragma unroll
  for (int i = 0; i < 4; ++i) {
    int c1 = c0 + h0[i];
    if (c0 < K && c1 >= K) s_tb = tid * 4 + i;  // unique crossing bucket
    c0 = c1;
  }
  __syncthreads();
  const int tb = s_tb;
  const unsigned lo = (unsigned)tb << 21;
  const unsigned hi = (unsigned)(tb + 1) << 21;

  // pass 2: emit sure-ins, collect boundary candidates
  for (int n = tid; n < N; n += KT) {
    float x = base[n * 3], y = base[n * 3 + 1], z = base[n * 3 + 2];
    float d = sqdist(x, y, z, cx, cy, cz);
    unsigned bits = __float_as_uint(d);
    if (bits < lo) {
      int pos = atomicAdd(&s_nin, 1);
      float* p = patches + ((size_t)blk * K + pos) * 3;
      p[0] = __fsub_rn(x, cx); p[1] = __fsub_rn(y, cy); p[2] = __fsub_rn(z, cz);
    } else if (bits < hi) {
      int q = atomicAdd(&s_ncand, 1);
      if (q < CAP) { cb[q] = bits; ci[q] = n; }
    }
  }
  __syncthreads();

  // exact rank-select among boundary candidates: (bits, idx) lexicographic
  const int nin = s_nin;
  const int ncand = min(s_ncand, CAP);
  const int nsel = K - nin;
  for (int j = tid; j < ncand; j += KT) {
    unsigned bj = cb[j];
    int ij = ci[j];
    int rank = 0;
    for (int i2 = 0; i2 < ncand; ++i2) {
      unsigned bv = cb[i2];
      int iv = ci[i2];
      rank += (bv < bj || (bv == bj && iv < ij)) ? 1 : 0;
    }
    if (rank < nsel) {
      float x = base[ij * 3], y = base[ij * 3 + 1], z = base[ij * 3 + 2];
      float* p = patches + ((size_t)blk * K + nin + rank) * 3;
      p[0] = __fsub_rn(x, cx); p[1] = __fsub_rn(y, cy); p[2] = __fsub_rn(z, cz);
    }
  }
}

// ---------------------------------------------------------------- MLP ------
// One block per patch. h1/h2 staged in LDS, rows XOR-swizzled so the b128
// writes are conflict-light; reads are uniform-address broadcasts.
constexpr int MT = 128;

__global__ __launch_bounds__(MT) void mlp_kernel(
    const float* __restrict__ patches,
    const float* __restrict__ W1, const float* __restrict__ b1,
    const float* __restrict__ g1, const float* __restrict__ bt1,
    const float* __restrict__ W2, const float* __restrict__ b2,
    const float* __restrict__ g2, const float* __restrict__ bt2,
    const float* __restrict__ W3, const float* __restrict__ b3,
    const float* __restrict__ g3, const float* __restrict__ bt3,
    float* __restrict__ tokens) {
  const int pm = blockIdx.x;
  const int tid = threadIdx.x;
  __shared__ float xs[3][K];
  __shared__ float h1s[64 * K];
  __shared__ float h2s[128 * K];
  __shared__ float pms[2][EMB];

  const float* patch = patches + (size_t)pm * (K * 3);
  if (tid < 96) xs[tid % 3][tid / 3] = patch[tid];
  __syncthreads();

  const int cg = tid & 63;
  const int half = tid >> 6;
  const int pt0 = half * 16;
  const float rs = 1.0f / sqrtf(1.0f + 1e-5f);

  // L1: 3 -> 64
  {
    const int c = cg;
    const float w0 = W1[c], w1 = W1[64 + c], w2 = W1[128 + c];
    const float bb = b1[c];
    const float sc = g1[c] * rs, be = bt1[c];
    float o[16];
#pragma unroll
    for (int p = 0; p < 16; ++p) {
      int pt = pt0 + p;
      float a = xs[0][pt] * w0 + xs[1][pt] * w1 + xs[2][pt] * w2 + bb;
      o[p] = fmaxf(a * sc + be, 0.0f);
    }
    const int so = (c & 7) << 2;
#pragma unroll
    for (int p4 = 0; p4 < 16; p4 += 4) {
      *(float4*)&h1s[c * K + ((pt0 + p4) ^ so)] =
          make_float4(o[p4], o[p4 + 1], o[p4 + 2], o[p4 + 3]);
    }
  }
  __syncthreads();

  // L2: 64 -> 128, c-tile 2 x pt-tile 16
  {
    const int c = cg * 2;
    float acc0[16], acc1[16];
    const float bb0 = b2[c], bb1 = b2[c + 1];
#pragma unroll
    for (int p = 0; p < 16; ++p) { acc0[p] = bb0; acc1[p] = bb1; }
    for (int k = 0; k < 64; ++k) {
      const float2 w = *(const float2*)(W2 + k * 128 + c);
      const int so = (k & 7) << 2;
      float4 x0 = *(const float4*)&h1s[k * K + ((pt0 + 0) ^ so)];
      float4 x1 = *(const float4*)&h1s[k * K + ((pt0 + 4) ^ so)];
      float4 x2 = *(const float4*)&h1s[k * K + ((pt0 + 8) ^ so)];
      float4 x3 = *(const float4*)&h1s[k * K + ((pt0 + 12) ^ so)];
      float xv[16] = {x0.x, x0.y, x0.z, x0.w, x1.x, x1.y, x1.z, x1.w,
                      x2.x, x2.y, x2.z, x2.w, x3.x, x3.y, x3.z, x3.w};
#pragma unroll
      for (int p = 0; p < 16; ++p) {
        acc0[p] += xv[p] * w.x;
        acc1[p] += xv[p] * w.y;
      }
    }
    const float sc0 = g2[c] * rs, be0 = bt2[c];
    const float sc1 = g2[c + 1] * rs, be1 = bt2[c + 1];
    float o0[16], o1[16];
#pragma unroll
    for (int p = 0; p < 16; ++p) {
      o0[p] = fmaxf(acc0[p] * sc0 + be0, 0.0f);
      o1[p] = fmaxf(acc1[p] * sc1 + be1, 0.0f);
    }
    const int soa = (c & 7) << 2, sob = ((c + 1) & 7) << 2;
#pragma unroll
    for (int p4 = 0; p4 < 16; p4 += 4) {
      *(float4*)&h2s[c * K + ((pt0 + p4) ^ soa)] =
          make_float4(o0[p4], o0[p4 + 1], o0[p4 + 2], o0[p4 + 3]);
      *(float4*)&h2s[(c + 1) * K + ((pt0 + p4) ^ sob)] =
          make_float4(o1[p4], o1[p4 + 1], o1[p4 + 2], o1[p4 + 3]);
    }
  }
  __syncthreads();

  // L3: 128 -> 256, c-tile 4 x pt-tile 16, fused BN+ReLU+max over its pts
  {
    const int c = cg * 4;
    float acc[4][16];
#pragma unroll
    for (int i = 0; i < 4; ++i) {
      const float bb = b3[c + i];
#pragma unroll
      for (int p = 0; p < 16; ++p) acc[i][p] = bb;
    }
    for (int k = 0; k < 128; ++k) {
      const float4 w = *(const float4*)(W3 + (size_t)k * 256 + c);
      const int so = (k & 7) << 2;
      float4 x0 = *(const float4*)&h2s[k * K + ((pt0 + 0) ^ so)];
      float4 x1 = *(const float4*)&h2s[k * K + ((pt0 + 4) ^ so)];
      float4 x2 = *(const float4*)&h2s[k * K + ((pt0 + 8) ^ so)];
      float4 x3 = *(const float4*)&h2s[k * K + ((pt0 + 12) ^ so)];
      float xv[16] = {x0.x, x0.y, x0.z, x0.w, x1.x, x1.y, x1.z, x1.w,
                      x2.x, x2.y, x2.z, x2.w, x3.x, x3.y, x3.z, x3.w};
#pragma unroll
      for (int p = 0; p < 16; ++p) {
        acc[0][p] += xv[p] * w.x;
        acc[1][p] += xv[p] * w.y;
        acc[2][p] += xv[p] * w.z;
        acc[3][p] += xv[p] * w.w;
      }
    }
#pragma unroll
    for (int i = 0; i < 4; ++i) {
      const float sc = g3[c + i] * rs, be = bt3[c + i];
      float mx = 0.0f;  // ReLU outputs are >= 0, so 0 is a safe identity
#pragma unroll
      for (int p = 0; p < 16; ++p)
        mx = fmaxf(mx, fmaxf(acc[i][p] * sc + be, 0.0f));
      pms[half][c + i] = mx;
    }
  }
  __syncthreads();

  {
    const int c2 = tid * 2;
    float* to = tokens + (size_t)pm * EMB;
    to[c2] = fmaxf(pms[0][c2], pms[1][c2]);
    to[c2 + 1] = fmaxf(pms[0][c2 + 1], pms[1][c2 + 1]);
  }
}

// ------------------------------------------------------------- launcher ----
extern "C" void kernel_launch(void* const* d_in, const int* in_sizes, int n_in,
                              void* d_out, int out_size, void* d_ws,
                              size_t ws_size, hipStream_t stream) {
  const float* xyz = (const float*)d_in[0];
  const float* W1 = (const float*)d_in[1];
  const float* b1 = (const float*)d_in[2];
  const float* g1 = (const float*)d_in[3];
  const float* bt1 = (const float*)d_in[4];
  const float* W2 = (const float*)d_in[5];
  const float* b2 = (const float*)d_in[6];
  const float* g2 = (const float*)d_in[7];
  const float* bt2 = (const float*)d_in[8];
  const float* W3 = (const float*)d_in[9];
  const float* b3 = (const float*)d_in[10];
  const float* g3 = (const float*)d_in[11];
  const float* bt3 = (const float*)d_in[12];

  float* tokens = (float*)d_out;                       // (B,M,EMB)
  float* centers = tokens + (size_t)B * M * EMB;       // (B,M,3)
  float* patches = (float*)d_ws;                       // (B*M, K, 3)

  fps_kernel<<<B, FPS_T, 0, stream>>>(xyz, centers);
  knn_kernel<<<B * M, KT, 0, stream>>>(xyz, centers, patches);
  mlp_kernel<<<B * M, MT, 0, stream>>>(patches, W1, b1, g1, bt1, W2, b2, g2,
                                       bt2, W3, b3, g3, bt3, tokens);
}

// Round 6
// 813.363 us; speedup vs baseline: 1.0610x; 1.0610x over previous
//
#include <hip/hip_runtime.h>

// Problem constants (fixed by setup_inputs)
constexpr int B   = 16;
constexpr int N   = 16384;
constexpr int M   = 256;   // n_centers
constexpr int K   = 32;    // knn
constexpr int EMB = 256;

// Exact (non-contracted) squared distance in the reference's association
// order: ((dx*dx + dy*dy) + dz*dz). Must be bit-identical to XLA CPU so the
// FPS argmax / kNN top-k selections match.
__device__ __forceinline__ float sqdist(float px, float py, float pz,
                                        float cx, float cy, float cz) {
  float dx = __fsub_rn(px, cx);
  float dy = __fsub_rn(py, cy);
  float dz = __fsub_rn(pz, cz);
  return __fadd_rn(__fadd_rn(__fmul_rn(dx, dx), __fmul_rn(dy, dy)),
                   __fmul_rn(dz, dz));
}

// ---------------------------------------------------------------- FPS ------
// 512 threads x 32 pts/thread. All point coords + running distances live in
// VGPRs (128 floats/thread -> needs the 256-VGPR budget from min-2-waves/EU;
// the old 1024-thread version got 48 VGPRs and spilled everything).
// One __syncthreads per iteration: wave leaders publish (val,idx) partials to
// double-buffered LDS; after the barrier EVERY thread reduces the 8 partials
// and broadcast-loads the next center from global (L1/L2 hit).
constexpr int FT = 512;
constexpr int FP = N / FT;        // 32 points per thread
constexpr int FW = FT / 64;       // 8 waves

__global__ __launch_bounds__(FT, 2) void fps_kernel(
    const float* __restrict__ xyz, float* __restrict__ centers) {
  const int b = blockIdx.x;
  const int tid = threadIdx.x;
  const float* base = xyz + (size_t)b * N * 3;

  float px[FP], py[FP], pz[FP], dist[FP];
#pragma unroll
  for (int j = 0; j < FP; ++j) {
    int n = tid + j * FT;
    px[j] = base[n * 3 + 0];
    py[j] = base[n * 3 + 1];
    pz[j] = base[n * 3 + 2];
    dist[j] = __builtin_inff();
  }

  __shared__ float s_pv[2][FW];
  __shared__ int s_pn[2][FW];

  // deterministic start: carry = point 0
  float cx = base[0], cy = base[1], cz = base[2];

  for (int it = 0; it < M; ++it) {
    if (tid == 0) {  // emit current carry (matches lax.scan semantics)
      float* co = centers + ((size_t)b * M + it) * 3;
      co[0] = cx; co[1] = cy; co[2] = cz;
    }
    const int p = it & 1;

    // update running min-distances; track per-thread max (value, local j)
    float bv = -1.0f;
    int bj = 0;
#pragma unroll
    for (int j = 0; j < FP; ++j) {
      float d = sqdist(px[j], py[j], pz[j], cx, cy, cz);
      float nd = fminf(dist[j], d);
      dist[j] = nd;
      bool g = nd > bv;          // strict > : first (lowest j) wins ties
      bv = g ? nd : bv;
      bj = g ? j : bj;           // inline-const select, no index array
    }
    int bn = bj * FT + tid;      // global point index

    // wave-level argmax, tie -> lowest global index
#pragma unroll
    for (int mm = 32; mm >= 1; mm >>= 1) {
      float ov = __shfl_xor(bv, mm, 64);
      int on = __shfl_xor(bn, mm, 64);
      if (ov > bv || (ov == bv && on < bn)) { bv = ov; bn = on; }
    }
    if ((tid & 63) == 0) {
      s_pv[p][tid >> 6] = bv;
      s_pn[p][tid >> 6] = bn;
    }
    __syncthreads();

    // every thread reduces the 8 wave partials (broadcast LDS reads)
    float v = s_pv[p][0];
    int n = s_pn[p][0];
#pragma unroll
    for (int w = 1; w < FW; ++w) {
      float ov = s_pv[p][w];
      int on = s_pn[p][w];
      if (ov > v || (ov == v && on < n)) { v = ov; n = on; }
    }
    // broadcast-load next center (same address across the wave -> 1 fetch)
    cx = base[(size_t)n * 3 + 0];
    cy = base[(size_t)n * 3 + 1];
    cz = base[(size_t)n * 3 + 2];
    // no second barrier: double-buffered partials make it race-free
  }
}

// ---------------------------------------------------------------- kNN ------
// Bucket-select on float bit prefixes (monotone for d >= 0). Only the SET of
// 32 nearest matters (max-pool later), so slots are written in arbitrary
// order; boundary-bucket ties resolved exactly by (bits, index).
constexpr int KT = 256;
constexpr int CAP = 512;
constexpr int NBUCKET = 1024;

__global__ __launch_bounds__(KT) void knn_kernel(
    const float* __restrict__ xyz, const float* __restrict__ centers,
    float* __restrict__ patches) {
  const int blk = blockIdx.x;      // b*M + m
  const int b = blk >> 8;          // M == 256
  const int tid = threadIdx.x;
  const float* base = xyz + (size_t)b * N * 3;

  __shared__ int hist[NBUCKET];
  __shared__ unsigned cb[CAP];
  __shared__ int ci[CAP];
  __shared__ int s_nin, s_ncand, s_tb;
  __shared__ int s_wsum[KT / 64];
  __shared__ float s_cc[3];

  if (tid == 0) {
    const float* c = centers + (size_t)blk * 3;
    s_cc[0] = c[0]; s_cc[1] = c[1]; s_cc[2] = c[2];
    s_nin = 0; s_ncand = 0;
  }
  for (int i = tid; i < NBUCKET; i += KT) hist[i] = 0;
  __syncthreads();

  const float cx = s_cc[0], cy = s_cc[1], cz = s_cc[2];

  // pass 1: histogram of 10-bit float prefixes
  for (int n = tid; n < N; n += KT) {
    float d = sqdist(base[n * 3], base[n * 3 + 1], base[n * 3 + 2], cx, cy, cz);
    atomicAdd(&hist[__float_as_uint(d) >> 21], 1);
  }
  __syncthreads();

  // block scan over 1024 buckets (4 per thread) to find threshold bucket
  int h0[4];
  int loc = 0;
#pragma unroll
  for (int i = 0; i < 4; ++i) { h0[i] = hist[tid * 4 + i]; loc += h0[i]; }
  int lane = tid & 63, wid = tid >> 6;
  int scan = loc;
  for (int off = 1; off < 64; off <<= 1) {
    int o = __shfl_up(scan, off, 64);
    if (lane >= off) scan += o;
  }
  if (lane == 63) s_wsum[wid] = scan;
  __syncthreads();
  int woff = 0;
  for (int w = 0; w < wid; ++w) woff += s_wsum[w];
  int c0 = woff + scan - loc;  // count strictly below this thread's buckets
#pragma unroll
  for (int i = 0; i < 4; ++i) {
    int c1 = c0 + h0[i];
    if (c0 < K && c1 >= K) s_tb = tid * 4 + i;  // unique crossing bucket
    c0 = c1;
  }
  __syncthreads();
  const int tb = s_tb;
  const unsigned lo = (unsigned)tb << 21;
  const unsigned hi = (unsigned)(tb + 1) << 21;

  // pass 2: emit sure-ins, collect boundary candidates
  for (int n = tid; n < N; n += KT) {
    float x = base[n * 3], y = base[n * 3 + 1], z = base[n * 3 + 2];
    float d = sqdist(x, y, z, cx, cy, cz);
    unsigned bits = __float_as_uint(d);
    if (bits < lo) {
      int pos = atomicAdd(&s_nin, 1);
      float* p = patches + ((size_t)blk * K + pos) * 3;
      p[0] = __fsub_rn(x, cx); p[1] = __fsub_rn(y, cy); p[2] = __fsub_rn(z, cz);
    } else if (bits < hi) {
      int q = atomicAdd(&s_ncand, 1);
      if (q < CAP) { cb[q] = bits; ci[q] = n; }
    }
  }
  __syncthreads();

  // exact rank-select among boundary candidates: (bits, idx) lexicographic
  const int nin = s_nin;
  const int ncand = min(s_ncand, CAP);
  const int nsel = K - nin;
  for (int j = tid; j < ncand; j += KT) {
    unsigned bj = cb[j];
    int ij = ci[j];
    int rank = 0;
    for (int i2 = 0; i2 < ncand; ++i2) {
      unsigned bv = cb[i2];
      int iv = ci[i2];
      rank += (bv < bj || (bv == bj && iv < ij)) ? 1 : 0;
    }
    if (rank < nsel) {
      float x = base[ij * 3], y = base[ij * 3 + 1], z = base[ij * 3 + 2];
      float* p = patches + ((size_t)blk * K + nin + rank) * 3;
      p[0] = __fsub_rn(x, cx); p[1] = __fsub_rn(y, cy); p[2] = __fsub_rn(z, cz);
    }
  }
}

// ---------------------------------------------------------------- MLP ------
// One block per patch. h1/h2 staged in LDS, rows XOR-swizzled so the b128
// writes are conflict-light; reads are uniform-address broadcasts.
constexpr int MT = 128;

__global__ __launch_bounds__(MT) void mlp_kernel(
    const float* __restrict__ patches,
    const float* __restrict__ W1, const float* __restrict__ b1,
    const float* __restrict__ g1, const float* __restrict__ bt1,
    const float* __restrict__ W2, const float* __restrict__ b2,
    const float* __restrict__ g2, const float* __restrict__ bt2,
    const float* __restrict__ W3, const float* __restrict__ b3,
    const float* __restrict__ g3, const float* __restrict__ bt3,
    float* __restrict__ tokens) {
  const int pm = blockIdx.x;
  const int tid = threadIdx.x;
  __shared__ float xs[3][K];
  __shared__ float h1s[64 * K];
  __shared__ float h2s[128 * K];
  __shared__ float pms[2][EMB];

  const float* patch = patches + (size_t)pm * (K * 3);
  if (tid < 96) xs[tid % 3][tid / 3] = patch[tid];
  __syncthreads();

  const int cg = tid & 63;
  const int half = tid >> 6;
  const int pt0 = half * 16;
  const float rs = 1.0f / sqrtf(1.0f + 1e-5f);

  // L1: 3 -> 64
  {
    const int c = cg;
    const float w0 = W1[c], w1 = W1[64 + c], w2 = W1[128 + c];
    const float bb = b1[c];
    const float sc = g1[c] * rs, be = bt1[c];
    float o[16];
#pragma unroll
    for (int p = 0; p < 16; ++p) {
      int pt = pt0 + p;
      float a = xs[0][pt] * w0 + xs[1][pt] * w1 + xs[2][pt] * w2 + bb;
      o[p] = fmaxf(a * sc + be, 0.0f);
    }
    const int so = (c & 7) << 2;
#pragma unroll
    for (int p4 = 0; p4 < 16; p4 += 4) {
      *(float4*)&h1s[c * K + ((pt0 + p4) ^ so)] =
          make_float4(o[p4], o[p4 + 1], o[p4 + 2], o[p4 + 3]);
    }
  }
  __syncthreads();

  // L2: 64 -> 128, c-tile 2 x pt-tile 16
  {
    const int c = cg * 2;
    float acc0[16], acc1[16];
    const float bb0 = b2[c], bb1 = b2[c + 1];
#pragma unroll
    for (int p = 0; p < 16; ++p) { acc0[p] = bb0; acc1[p] = bb1; }
    for (int k = 0; k < 64; ++k) {
      const float2 w = *(const float2*)(W2 + k * 128 + c);
      const int so = (k & 7) << 2;
      float4 x0 = *(const float4*)&h1s[k * K + ((pt0 + 0) ^ so)];
      float4 x1 = *(const float4*)&h1s[k * K + ((pt0 + 4) ^ so)];
      float4 x2 = *(const float4*)&h1s[k * K + ((pt0 + 8) ^ so)];
      float4 x3 = *(const float4*)&h1s[k * K + ((pt0 + 12) ^ so)];
      float xv[16] = {x0.x, x0.y, x0.z, x0.w, x1.x, x1.y, x1.z, x1.w,
                      x2.x, x2.y, x2.z, x2.w, x3.x, x3.y, x3.z, x3.w};
#pragma unroll
      for (int p = 0; p < 16; ++p) {
        acc0[p] += xv[p] * w.x;
        acc1[p] += xv[p] * w.y;
      }
    }
    const float sc0 = g2[c] * rs, be0 = bt2[c];
    const float sc1 = g2[c + 1] * rs, be1 = bt2[c + 1];
    float o0[16], o1[16];
#pragma unroll
    for (int p = 0; p < 16; ++p) {
      o0[p] = fmaxf(acc0[p] * sc0 + be0, 0.0f);
      o1[p] = fmaxf(acc1[p] * sc1 + be1, 0.0f);
    }
    const int soa = (c & 7) << 2, sob = ((c + 1) & 7) << 2;
#pragma unroll
    for (int p4 = 0; p4 < 16; p4 += 4) {
      *(float4*)&h2s[c * K + ((pt0 + p4) ^ soa)] =
          make_float4(o0[p4], o0[p4 + 1], o0[p4 + 2], o0[p4 + 3]);
      *(float4*)&h2s[(c + 1) * K + ((pt0 + p4) ^ sob)] =
          make_float4(o1[p4], o1[p4 + 1], o1[p4 + 2], o1[p4 + 3]);
    }
  }
  __syncthreads();

  // L3: 128 -> 256, c-tile 4 x pt-tile 16, fused BN+ReLU+max over its pts
  {
    const int c = cg * 4;
    float acc[4][16];
#pragma unroll
    for (int i = 0; i < 4; ++i) {
      const float bb = b3[c + i];
#pragma unroll
      for (int p = 0; p < 16; ++p) acc[i][p] = bb;
    }
    for (int k = 0; k < 128; ++k) {
      const float4 w = *(const float4*)(W3 + (size_t)k * 256 + c);
      const int so = (k & 7) << 2;
      float4 x0 = *(const float4*)&h2s[k * K + ((pt0 + 0) ^ so)];
      float4 x1 = *(const float4*)&h2s[k * K + ((pt0 + 4) ^ so)];
      float4 x2 = *(const float4*)&h2s[k * K + ((pt0 + 8) ^ so)];
      float4 x3 = *(const float4*)&h2s[k * K + ((pt0 + 12) ^ so)];
      float xv[16] = {x0.x, x0.y, x0.z, x0.w, x1.x, x1.y, x1.z, x1.w,
                      x2.x, x2.y, x2.z, x2.w, x3.x, x3.y, x3.z, x3.w};
#pragma unroll
      for (int p = 0; p < 16; ++p) {
        acc[0][p] += xv[p] * w.x;
        acc[1][p] += xv[p] * w.y;
        acc[2][p] += xv[p] * w.z;
        acc[3][p] += xv[p] * w.w;
      }
    }
#pragma unroll
    for (int i = 0; i < 4; ++i) {
      const float sc = g3[c + i] * rs, be = bt3[c + i];
      float mx = 0.0f;  // ReLU outputs are >= 0, so 0 is a safe identity
#pragma unroll
      for (int p = 0; p < 16; ++p)
        mx = fmaxf(mx, fmaxf(acc[i][p] * sc + be, 0.0f));
      pms[half][c + i] = mx;
    }
  }
  __syncthreads();

  {
    const int c2 = tid * 2;
    float* to = tokens + (size_t)pm * EMB;
    to[c2] = fmaxf(pms[0][c2], pms[1][c2]);
    to[c2 + 1] = fmaxf(pms[0][c2 + 1], pms[1][c2 + 1]);
  }
}

// ------------------------------------------------------------- launcher ----
extern "C" void kernel_launch(void* const* d_in, const int* in_sizes, int n_in,
                              void* d_out, int out_size, void* d_ws,
                              size_t ws_size, hipStream_t stream) {
  const float* xyz = (const float*)d_in[0];
  const float* W1 = (const float*)d_in[1];
  const float* b1 = (const float*)d_in[2];
  const float* g1 = (const float*)d_in[3];
  const float* bt1 = (const float*)d_in[4];
  const float* W2 = (const float*)d_in[5];
  const float* b2 = (const float*)d_in[6];
  const float* g2 = (const float*)d_in[7];
  const float* bt2 = (const float*)d_in[8];
  const float* W3 = (const float*)d_in[9];
  const float* b3 = (const float*)d_in[10];
  const float* g3 = (const float*)d_in[11];
  const float* bt3 = (const float*)d_in[12];

  float* tokens = (float*)d_out;                       // (B,M,EMB)
  float* centers = tokens + (size_t)B * M * EMB;       // (B,M,3)
  float* patches = (float*)d_ws;                       // (B*M, K, 3)

  fps_kernel<<<B, FT, 0, stream>>>(xyz, centers);
  knn_kernel<<<B * M, KT, 0, stream>>>(xyz, centers, patches);
  mlp_kernel<<<B * M, MT, 0, stream>>>(patches, W1, b1, g1, bt1, W2, b2, g2,
                                       bt2, W3, b3, g3, bt3, tokens);
}

// Round 7
// 812.184 us; speedup vs baseline: 1.0626x; 1.0015x over previous
//
#include <hip/hip_runtime.h>

// Problem constants (fixed by setup_inputs)
constexpr int B   = 16;
constexpr int N   = 16384;
constexpr int M   = 256;   // n_centers
constexpr int K   = 32;    // knn
constexpr int EMB = 256;

// Exact (non-contracted) squared distance in the reference's association
// order: ((dx*dx + dy*dy) + dz*dz). Must be bit-identical to XLA CPU so the
// FPS argmax / kNN top-k selections match.
__device__ __forceinline__ float sqdist(float px, float py, float pz,
                                        float cx, float cy, float cz) {
  float dx = __fsub_rn(px, cx);
  float dy = __fsub_rn(py, cy);
  float dz = __fsub_rn(pz, cz);
  return __fadd_rn(__fadd_rn(__fmul_rn(dx, dx), __fmul_rn(dy, dy)),
                   __fmul_rn(dz, dz));
}

// ---------------------------------------------------------------- FPS ------
// 512 threads x 32 pts/thread. Point coords + running distances kept in
// NAMED SCALARS (arrays were not SROA-promoted by hipcc: r5 VGPR=48, r6
// VGPR=84 -> both spilled to scratch, 2.3us/iter latency-bound). Named
// scalars force register residence under the 256-VGPR cap from
// __launch_bounds__(512, 2).
constexpr int FT = 512;
constexpr int FP = N / FT;        // 32 points per thread
constexpr int FW = FT / 64;       // 8 waves
static_assert(FT == 512 && FP == 32, "macro expansion assumes 512x32");

#define FPS_REP(X) X(0) X(1) X(2) X(3) X(4) X(5) X(6) X(7) X(8) X(9) \
  X(10) X(11) X(12) X(13) X(14) X(15) X(16) X(17) X(18) X(19) \
  X(20) X(21) X(22) X(23) X(24) X(25) X(26) X(27) X(28) X(29) X(30) X(31)

__global__ __launch_bounds__(FT, 2) void fps_kernel(
    const float* __restrict__ xyz, float* __restrict__ centers) {
  const int b = blockIdx.x;
  const int tid = threadIdx.x;
  const float* base = xyz + (size_t)b * N * 3;

#define FPS_DECL(i) float px##i, py##i, pz##i, ds##i;
  FPS_REP(FPS_DECL)
#undef FPS_DECL

#define FPS_LOAD(i) { const int n = tid + (i) * FT;      \
    px##i = base[n * 3 + 0];                              \
    py##i = base[n * 3 + 1];                              \
    pz##i = base[n * 3 + 2];                              \
    ds##i = __builtin_inff(); }
  FPS_REP(FPS_LOAD)
#undef FPS_LOAD

  __shared__ float s_pv[2][FW];
  __shared__ int s_pn[2][FW];

  // deterministic start: carry = point 0
  float cx = base[0], cy = base[1], cz = base[2];

  for (int it = 0; it < M; ++it) {
    if (tid == 0) {  // emit current carry (matches lax.scan semantics)
      float* co = centers + ((size_t)b * M + it) * 3;
      co[0] = cx; co[1] = cy; co[2] = cz;
    }
    const int p = it & 1;

    // update running min-distances; track per-thread max (value, local j).
    // strict > : first (lowest j) wins ties; j is an inline-const cndmask.
    float bv = -1.0f;
    int bj = 0;
#define FPS_UPD(i) {                                       \
    float dx = __fsub_rn(px##i, cx);                       \
    float dy = __fsub_rn(py##i, cy);                       \
    float dz = __fsub_rn(pz##i, cz);                       \
    float dd = __fadd_rn(__fadd_rn(__fmul_rn(dx, dx),      \
                                   __fmul_rn(dy, dy)),     \
                         __fmul_rn(dz, dz));               \
    float nd = fminf(ds##i, dd);                           \
    ds##i = nd;                                            \
    bool g = nd > bv;                                      \
    bv = g ? nd : bv;                                      \
    bj = g ? (i) : bj; }
    FPS_REP(FPS_UPD)
#undef FPS_UPD
    int bn = (bj << 9) + tid;  // global point index (FT == 512)

    // wave-level argmax, tie -> lowest global index
#pragma unroll
    for (int mm = 32; mm >= 1; mm >>= 1) {
      float ov = __shfl_xor(bv, mm, 64);
      int on = __shfl_xor(bn, mm, 64);
      if (ov > bv || (ov == bv && on < bn)) { bv = ov; bn = on; }
    }
    if ((tid & 63) == 0) {
      s_pv[p][tid >> 6] = bv;
      s_pn[p][tid >> 6] = bn;
    }
    __syncthreads();

    // every thread reduces the 8 wave partials (broadcast LDS reads)
    float v = s_pv[p][0];
    int n = s_pn[p][0];
#pragma unroll
    for (int w = 1; w < FW; ++w) {
      float ov = s_pv[p][w];
      int on = s_pn[p][w];
      if (ov > v || (ov == v && on < n)) { v = ov; n = on; }
    }
    // broadcast-load next center (same address across the wave -> 1 fetch)
    cx = base[(size_t)n * 3 + 0];
    cy = base[(size_t)n * 3 + 1];
    cz = base[(size_t)n * 3 + 2];
    // no second barrier: double-buffered partials make it race-free
  }
}

// ---------------------------------------------------------------- kNN ------
// Bucket-select on float bit prefixes (monotone for d >= 0). Only the SET of
// 32 nearest matters (max-pool later), so slots are written in arbitrary
// order; boundary-bucket ties resolved exactly by (bits, index).
constexpr int KT = 256;
constexpr int CAP = 512;
constexpr int NBUCKET = 1024;

__global__ __launch_bounds__(KT) void knn_kernel(
    const float* __restrict__ xyz, const float* __restrict__ centers,
    float* __restrict__ patches) {
  const int blk = blockIdx.x;      // b*M + m
  const int b = blk >> 8;          // M == 256
  const int tid = threadIdx.x;
  const float* base = xyz + (size_t)b * N * 3;

  __shared__ int hist[NBUCKET];
  __shared__ unsigned cb[CAP];
  __shared__ int ci[CAP];
  __shared__ int s_nin, s_ncand, s_tb;
  __shared__ int s_wsum[KT / 64];
  __shared__ float s_cc[3];

  if (tid == 0) {
    const float* c = centers + (size_t)blk * 3;
    s_cc[0] = c[0]; s_cc[1] = c[1]; s_cc[2] = c[2];
    s_nin = 0; s_ncand = 0;
  }
  for (int i = tid; i < NBUCKET; i += KT) hist[i] = 0;
  __syncthreads();

  const float cx = s_cc[0], cy = s_cc[1], cz = s_cc[2];

  // pass 1: histogram of 10-bit float prefixes
  for (int n = tid; n < N; n += KT) {
    float d = sqdist(base[n * 3], base[n * 3 + 1], base[n * 3 + 2], cx, cy, cz);
    atomicAdd(&hist[__float_as_uint(d) >> 21], 1);
  }
  __syncthreads();

  // block scan over 1024 buckets (4 per thread) to find threshold bucket
  int h0[4];
  int loc = 0;
#pragma unroll
  for (int i = 0; i < 4; ++i) { h0[i] = hist[tid * 4 + i]; loc += h0[i]; }
  int lane = tid & 63, wid = tid >> 6;
  int scan = loc;
  for (int off = 1; off < 64; off <<= 1) {
    int o = __shfl_up(scan, off, 64);
    if (lane >= off) scan += o;
  }
  if (lane == 63) s_wsum[wid] = scan;
  __syncthreads();
  int woff = 0;
  for (int w = 0; w < wid; ++w) woff += s_wsum[w];
  int c0 = woff + scan - loc;  // count strictly below this thread's buckets
#pragma unroll
  for (int i = 0; i < 4; ++i) {
    int c1 = c0 + h0[i];
    if (c0 < K && c1 >= K) s_tb = tid * 4 + i;  // unique crossing bucket
    c0 = c1;
  }
  __syncthreads();
  const int tb = s_tb;
  const unsigned lo = (unsigned)tb << 21;
  const unsigned hi = (unsigned)(tb + 1) << 21;

  // pass 2: emit sure-ins, collect boundary candidates
  for (int n = tid; n < N; n += KT) {
    float x = base[n * 3], y = base[n * 3 + 1], z = base[n * 3 + 2];
    float d = sqdist(x, y, z, cx, cy, cz);
    unsigned bits = __float_as_uint(d);
    if (bits < lo) {
      int pos = atomicAdd(&s_nin, 1);
      float* p = patches + ((size_t)blk * K + pos) * 3;
      p[0] = __fsub_rn(x, cx); p[1] = __fsub_rn(y, cy); p[2] = __fsub_rn(z, cz);
    } else if (bits < hi) {
      int q = atomicAdd(&s_ncand, 1);
      if (q < CAP) { cb[q] = bits; ci[q] = n; }
    }
  }
  __syncthreads();

  // exact rank-select among boundary candidates: (bits, idx) lexicographic
  const int nin = s_nin;
  const int ncand = min(s_ncand, CAP);
  const int nsel = K - nin;
  for (int j = tid; j < ncand; j += KT) {
    unsigned bj = cb[j];
    int ij = ci[j];
    int rank = 0;
    for (int i2 = 0; i2 < ncand; ++i2) {
      unsigned bv = cb[i2];
      int iv = ci[i2];
      rank += (bv < bj || (bv == bj && iv < ij)) ? 1 : 0;
    }
    if (rank < nsel) {
      float x = base[ij * 3], y = base[ij * 3 + 1], z = base[ij * 3 + 2];
      float* p = patches + ((size_t)blk * K + nin + rank) * 3;
      p[0] = __fsub_rn(x, cx); p[1] = __fsub_rn(y, cy); p[2] = __fsub_rn(z, cz);
    }
  }
}

// ---------------------------------------------------------------- MLP ------
// One block per patch. h1/h2 staged in LDS, rows XOR-swizzled so the b128
// writes are conflict-light; reads are uniform-address broadcasts.
constexpr int MT = 128;

__global__ __launch_bounds__(MT) void mlp_kernel(
    const float* __restrict__ patches,
    const float* __restrict__ W1, const float* __restrict__ b1,
    const float* __restrict__ g1, const float* __restrict__ bt1,
    const float* __restrict__ W2, const float* __restrict__ b2,
    const float* __restrict__ g2, const float* __restrict__ bt2,
    const float* __restrict__ W3, const float* __restrict__ b3,
    const float* __restrict__ g3, const float* __restrict__ bt3,
    float* __restrict__ tokens) {
  const int pm = blockIdx.x;
  const int tid = threadIdx.x;
  __shared__ float xs[3][K];
  __shared__ float h1s[64 * K];
  __shared__ float h2s[128 * K];
  __shared__ float pms[2][EMB];

  const float* patch = patches + (size_t)pm * (K * 3);
  if (tid < 96) xs[tid % 3][tid / 3] = patch[tid];
  __syncthreads();

  const int cg = tid & 63;
  const int half = tid >> 6;
  const int pt0 = half * 16;
  const float rs = 1.0f / sqrtf(1.0f + 1e-5f);

  // L1: 3 -> 64
  {
    const int c = cg;
    const float w0 = W1[c], w1 = W1[64 + c], w2 = W1[128 + c];
    const float bb = b1[c];
    const float sc = g1[c] * rs, be = bt1[c];
    float o[16];
#pragma unroll
    for (int p = 0; p < 16; ++p) {
      int pt = pt0 + p;
      float a = xs[0][pt] * w0 + xs[1][pt] * w1 + xs[2][pt] * w2 + bb;
      o[p] = fmaxf(a * sc + be, 0.0f);
    }
    const int so = (c & 7) << 2;
#pragma unroll
    for (int p4 = 0; p4 < 16; p4 += 4) {
      *(float4*)&h1s[c * K + ((pt0 + p4) ^ so)] =
          make_float4(o[p4], o[p4 + 1], o[p4 + 2], o[p4 + 3]);
    }
  }
  __syncthreads();

  // L2: 64 -> 128, c-tile 2 x pt-tile 16
  {
    const int c = cg * 2;
    float acc0[16], acc1[16];
    const float bb0 = b2[c], bb1 = b2[c + 1];
#pragma unroll
    for (int p = 0; p < 16; ++p) { acc0[p] = bb0; acc1[p] = bb1; }
    for (int k = 0; k < 64; ++k) {
      const float2 w = *(const float2*)(W2 + k * 128 + c);
      const int so = (k & 7) << 2;
      float4 x0 = *(const float4*)&h1s[k * K + ((pt0 + 0) ^ so)];
      float4 x1 = *(const float4*)&h1s[k * K + ((pt0 + 4) ^ so)];
      float4 x2 = *(const float4*)&h1s[k * K + ((pt0 + 8) ^ so)];
      float4 x3 = *(const float4*)&h1s[k * K + ((pt0 + 12) ^ so)];
      float xv[16] = {x0.x, x0.y, x0.z, x0.w, x1.x, x1.y, x1.z, x1.w,
                      x2.x, x2.y, x2.z, x2.w, x3.x, x3.y, x3.z, x3.w};
#pragma unroll
      for (int p = 0; p < 16; ++p) {
        acc0[p] += xv[p] * w.x;
        acc1[p] += xv[p] * w.y;
      }
    }
    const float sc0 = g2[c] * rs, be0 = bt2[c];
    const float sc1 = g2[c + 1] * rs, be1 = bt2[c + 1];
    float o0[16], o1[16];
#pragma unroll
    for (int p = 0; p < 16; ++p) {
      o0[p] = fmaxf(acc0[p] * sc0 + be0, 0.0f);
      o1[p] = fmaxf(acc1[p] * sc1 + be1, 0.0f);
    }
    const int soa = (c & 7) << 2, sob = ((c + 1) & 7) << 2;
#pragma unroll
    for (int p4 = 0; p4 < 16; p4 += 4) {
      *(float4*)&h2s[c * K + ((pt0 + p4) ^ soa)] =
          make_float4(o0[p4], o0[p4 + 1], o0[p4 + 2], o0[p4 + 3]);
      *(float4*)&h2s[(c + 1) * K + ((pt0 + p4) ^ sob)] =
          make_float4(o1[p4], o1[p4 + 1], o1[p4 + 2], o1[p4 + 3]);
    }
  }
  __syncthreads();

  // L3: 128 -> 256, c-tile 4 x pt-tile 16, fused BN+ReLU+max over its pts
  {
    const int c = cg * 4;
    float acc[4][16];
#pragma unroll
    for (int i = 0; i < 4; ++i) {
      const float bb = b3[c + i];
#pragma unroll
      for (int p = 0; p < 16; ++p) acc[i][p] = bb;
    }
    for (int k = 0; k < 128; ++k) {
      const float4 w = *(const float4*)(W3 + (size_t)k * 256 + c);
      const int so = (k & 7) << 2;
      float4 x0 = *(const float4*)&h2s[k * K + ((pt0 + 0) ^ so)];
      float4 x1 = *(const float4*)&h2s[k * K + ((pt0 + 4) ^ so)];
      float4 x2 = *(const float4*)&h2s[k * K + ((pt0 + 8) ^ so)];
      float4 x3 = *(const float4*)&h2s[k * K + ((pt0 + 12) ^ so)];
      float xv[16] = {x0.x, x0.y, x0.z, x0.w, x1.x, x1.y, x1.z, x1.w,
                      x2.x, x2.y, x2.z, x2.w, x3.x, x3.y, x3.z, x3.w};
#pragma unroll
      for (int p = 0; p < 16; ++p) {
        acc[0][p] += xv[p] * w.x;
        acc[1][p] += xv[p] * w.y;
        acc[2][p] += xv[p] * w.z;
        acc[3][p] += xv[p] * w.w;
      }
    }
#pragma unroll
    for (int i = 0; i < 4; ++i) {
      const float sc = g3[c + i] * rs, be = bt3[c + i];
      float mx = 0.0f;  // ReLU outputs are >= 0, so 0 is a safe identity
#pragma unroll
      for (int p = 0; p < 16; ++p)
        mx = fmaxf(mx, fmaxf(acc[i][p] * sc + be, 0.0f));
      pms[half][c + i] = mx;
    }
  }
  __syncthreads();

  {
    const int c2 = tid * 2;
    float* to = tokens + (size_t)pm * EMB;
    to[c2] = fmaxf(pms[0][c2], pms[1][c2]);
    to[c2 + 1] = fmaxf(pms[0][c2 + 1], pms[1][c2 + 1]);
  }
}

// ------------------------------------------------------------- launcher ----
extern "C" void kernel_launch(void* const* d_in, const int* in_sizes, int n_in,
                              void* d_out, int out_size, void* d_ws,
                              size_t ws_size, hipStream_t stream) {
  const float* xyz = (const float*)d_in[0];
  const float* W1 = (const float*)d_in[1];
  const float* b1 = (const float*)d_in[2];
  const float* g1 = (const float*)d_in[3];
  const float* bt1 = (const float*)d_in[4];
  const float* W2 = (const float*)d_in[5];
  const float* b2 = (const float*)d_in[6];
  const float* g2 = (const float*)d_in[7];
  const float* bt2 = (const float*)d_in[8];
  const float* W3 = (const float*)d_in[9];
  const float* b3 = (const float*)d_in[10];
  const float* g3 = (const float*)d_in[11];
  const float* bt3 = (const float*)d_in[12];

  float* tokens = (float*)d_out;                       // (B,M,EMB)
  float* centers = tokens + (size_t)B * M * EMB;       // (B,M,3)
  float* patches = (float*)d_ws;                       // (B*M, K, 3)

  fps_kernel<<<B, FT, 0, stream>>>(xyz, centers);
  knn_kernel<<<B * M, KT, 0, stream>>>(xyz, centers, patches);
  mlp_kernel<<<B * M, MT, 0, stream>>>(patches, W1, b1, g1, bt1, W2, b2, g2,
                                       bt2, W3, b3, g3, bt3, tokens);
}

// Round 8
// 808.968 us; speedup vs baseline: 1.0668x; 1.0040x over previous
//
#include <hip/hip_runtime.h>

// Problem constants (fixed by setup_inputs)
constexpr int B   = 16;
constexpr int N   = 16384;
constexpr int M   = 256;   // n_centers
constexpr int K   = 32;    // knn
constexpr int EMB = 256;

// Exact (non-contracted) squared distance in the reference's association
// order: ((dx*dx + dy*dy) + dz*dz). Must be bit-identical to XLA CPU so the
// FPS argmax / kNN top-k selections match.
__device__ __forceinline__ float sqdist(float px, float py, float pz,
                                        float cx, float cy, float cz) {
  float dx = __fsub_rn(px, cx);
  float dy = __fsub_rn(py, cy);
  float dz = __fsub_rn(pz, cz);
  return __fadd_rn(__fadd_rn(__fmul_rn(dx, dx), __fmul_rn(dy, dy)),
                   __fmul_rn(dz, dz));
}

// ---------------------------------------------------------------- FPS ------
// 512 threads x 32 pts/thread. r6/r7 showed VGPR=84, WRITE_SIZE=48KB: no
// spilling, but the compiler REMATERIALIZES the coord loads (const __restrict
// source) and re-reads all 196KB from L1/L2 every iteration -> latency-bound
// 2.3us/iter. The empty asm with "+v" makes each coord asm-defined, so remat
// is illegal and the values must stay resident in VGPRs (state=128 regs,
// budget=256 from __launch_bounds__(512,2)).
constexpr int FT = 512;
constexpr int FP = N / FT;        // 32 points per thread
constexpr int FW = FT / 64;       // 8 waves
static_assert(FT == 512 && FP == 32, "macro expansion assumes 512x32");

#define FPS_REP(X) X(0) X(1) X(2) X(3) X(4) X(5) X(6) X(7) X(8) X(9) \
  X(10) X(11) X(12) X(13) X(14) X(15) X(16) X(17) X(18) X(19) \
  X(20) X(21) X(22) X(23) X(24) X(25) X(26) X(27) X(28) X(29) X(30) X(31)

__global__ __launch_bounds__(FT, 2) void fps_kernel(
    const float* __restrict__ xyz, float* __restrict__ centers) {
  const int b = blockIdx.x;
  const int tid = threadIdx.x;
  const float* base = xyz + (size_t)b * N * 3;

#define FPS_DECL(i) float px##i, py##i, pz##i, ds##i;
  FPS_REP(FPS_DECL)
#undef FPS_DECL

#define FPS_LOAD(i) { const int n = tid + (i) * FT;      \
    px##i = base[n * 3 + 0];                              \
    py##i = base[n * 3 + 1];                              \
    pz##i = base[n * 3 + 2];                              \
    ds##i = __builtin_inff(); }
  FPS_REP(FPS_LOAD)
#undef FPS_LOAD

  // Pin coords in VGPRs: values become asm-defined -> the compiler can no
  // longer rematerialize the global loads inside the loop.
#define FPS_PIN(i) asm volatile("" : "+v"(px##i), "+v"(py##i), "+v"(pz##i));
  FPS_REP(FPS_PIN)
#undef FPS_PIN

  __shared__ float s_pv[2][FW];
  __shared__ int s_pn[2][FW];

  // deterministic start: carry = point 0
  float cx = base[0], cy = base[1], cz = base[2];

  for (int it = 0; it < M; ++it) {
    if (tid == 0) {  // emit current carry (matches lax.scan semantics)
      float* co = centers + ((size_t)b * M + it) * 3;
      co[0] = cx; co[1] = cy; co[2] = cz;
    }
    const int p = it & 1;

    // update running min-distances; track per-thread max (value, local j).
    // strict > : first (lowest j) wins ties; j is an inline-const cndmask.
    float bv = -1.0f;
    int bj = 0;
#define FPS_UPD(i) {                                       \
    float dx = __fsub_rn(px##i, cx);                       \
    float dy = __fsub_rn(py##i, cy);                       \
    float dz = __fsub_rn(pz##i, cz);                       \
    float dd = __fadd_rn(__fadd_rn(__fmul_rn(dx, dx),      \
                                   __fmul_rn(dy, dy)),     \
                         __fmul_rn(dz, dz));               \
    float nd = fminf(ds##i, dd);                           \
    ds##i = nd;                                            \
    bool g = nd > bv;                                      \
    bv = g ? nd : bv;                                      \
    bj = g ? (i) : bj; }
    FPS_REP(FPS_UPD)
#undef FPS_UPD
    int bn = (bj << 9) + tid;  // global point index (FT == 512)

    // wave-level argmax, tie -> lowest global index
#pragma unroll
    for (int mm = 32; mm >= 1; mm >>= 1) {
      float ov = __shfl_xor(bv, mm, 64);
      int on = __shfl_xor(bn, mm, 64);
      if (ov > bv || (ov == bv && on < bn)) { bv = ov; bn = on; }
    }
    if ((tid & 63) == 0) {
      s_pv[p][tid >> 6] = bv;
      s_pn[p][tid >> 6] = bn;
    }
    __syncthreads();

    // every thread reduces the 8 wave partials (broadcast LDS reads)
    float v = s_pv[p][0];
    int n = s_pn[p][0];
#pragma unroll
    for (int w = 1; w < FW; ++w) {
      float ov = s_pv[p][w];
      int on = s_pn[p][w];
      if (ov > v || (ov == v && on < n)) { v = ov; n = on; }
    }
    // broadcast-load next center (same address across the wave -> 1 fetch)
    cx = base[(size_t)n * 3 + 0];
    cy = base[(size_t)n * 3 + 1];
    cz = base[(size_t)n * 3 + 2];
    // no second barrier: double-buffered partials make it race-free
  }
}

// ---------------------------------------------------------------- kNN ------
// Bucket-select on float bit prefixes (monotone for d >= 0). Only the SET of
// 32 nearest matters (max-pool later), so slots are written in arbitrary
// order; boundary-bucket ties resolved exactly by (bits, index).
constexpr int KT = 256;
constexpr int CAP = 512;
constexpr int NBUCKET = 1024;

__global__ __launch_bounds__(KT) void knn_kernel(
    const float* __restrict__ xyz, const float* __restrict__ centers,
    float* __restrict__ patches) {
  const int blk = blockIdx.x;      // b*M + m
  const int b = blk >> 8;          // M == 256
  const int tid = threadIdx.x;
  const float* base = xyz + (size_t)b * N * 3;

  __shared__ int hist[NBUCKET];
  __shared__ unsigned cb[CAP];
  __shared__ int ci[CAP];
  __shared__ int s_nin, s_ncand, s_tb;
  __shared__ int s_wsum[KT / 64];
  __shared__ float s_cc[3];

  if (tid == 0) {
    const float* c = centers + (size_t)blk * 3;
    s_cc[0] = c[0]; s_cc[1] = c[1]; s_cc[2] = c[2];
    s_nin = 0; s_ncand = 0;
  }
  for (int i = tid; i < NBUCKET; i += KT) hist[i] = 0;
  __syncthreads();

  const float cx = s_cc[0], cy = s_cc[1], cz = s_cc[2];

  // pass 1: histogram of 10-bit float prefixes
  for (int n = tid; n < N; n += KT) {
    float d = sqdist(base[n * 3], base[n * 3 + 1], base[n * 3 + 2], cx, cy, cz);
    atomicAdd(&hist[__float_as_uint(d) >> 21], 1);
  }
  __syncthreads();

  // block scan over 1024 buckets (4 per thread) to find threshold bucket
  int h0[4];
  int loc = 0;
#pragma unroll
  for (int i = 0; i < 4; ++i) { h0[i] = hist[tid * 4 + i]; loc += h0[i]; }
  int lane = tid & 63, wid = tid >> 6;
  int scan = loc;
  for (int off = 1; off < 64; off <<= 1) {
    int o = __shfl_up(scan, off, 64);
    if (lane >= off) scan += o;
  }
  if (lane == 63) s_wsum[wid] = scan;
  __syncthreads();
  int woff = 0;
  for (int w = 0; w < wid; ++w) woff += s_wsum[w];
  int c0 = woff + scan - loc;  // count strictly below this thread's buckets
#pragma unroll
  for (int i = 0; i < 4; ++i) {
    int c1 = c0 + h0[i];
    if (c0 < K && c1 >= K) s_tb = tid * 4 + i;  // unique crossing bucket
    c0 = c1;
  }
  __syncthreads();
  const int tb = s_tb;
  const unsigned lo = (unsigned)tb << 21;
  const unsigned hi = (unsigned)(tb + 1) << 21;

  // pass 2: emit sure-ins, collect boundary candidates
  for (int n = tid; n < N; n += KT) {
    float x = base[n * 3], y = base[n * 3 + 1], z = base[n * 3 + 2];
    float d = sqdist(x, y, z, cx, cy, cz);
    unsigned bits = __float_as_uint(d);
    if (bits < lo) {
      int pos = atomicAdd(&s_nin, 1);
      float* p = patches + ((size_t)blk * K + pos) * 3;
      p[0] = __fsub_rn(x, cx); p[1] = __fsub_rn(y, cy); p[2] = __fsub_rn(z, cz);
    } else if (bits < hi) {
      int q = atomicAdd(&s_ncand, 1);
      if (q < CAP) { cb[q] = bits; ci[q] = n; }
    }
  }
  __syncthreads();

  // exact rank-select among boundary candidates: (bits, idx) lexicographic
  const int nin = s_nin;
  const int ncand = min(s_ncand, CAP);
  const int nsel = K - nin;
  for (int j = tid; j < ncand; j += KT) {
    unsigned bj = cb[j];
    int ij = ci[j];
    int rank = 0;
    for (int i2 = 0; i2 < ncand; ++i2) {
      unsigned bv = cb[i2];
      int iv = ci[i2];
      rank += (bv < bj || (bv == bj && iv < ij)) ? 1 : 0;
    }
    if (rank < nsel) {
      float x = base[ij * 3], y = base[ij * 3 + 1], z = base[ij * 3 + 2];
      float* p = patches + ((size_t)blk * K + nin + rank) * 3;
      p[0] = __fsub_rn(x, cx); p[1] = __fsub_rn(y, cy); p[2] = __fsub_rn(z, cz);
    }
  }
}

// ---------------------------------------------------------------- MLP ------
// One block per patch. h1/h2 staged in LDS, rows XOR-swizzled so the b128
// writes are conflict-light; reads are uniform-address broadcasts.
constexpr int MT = 128;

__global__ __launch_bounds__(MT) void mlp_kernel(
    const float* __restrict__ patches,
    const float* __restrict__ W1, const float* __restrict__ b1,
    const float* __restrict__ g1, const float* __restrict__ bt1,
    const float* __restrict__ W2, const float* __restrict__ b2,
    const float* __restrict__ g2, const float* __restrict__ bt2,
    const float* __restrict__ W3, const float* __restrict__ b3,
    const float* __restrict__ g3, const float* __restrict__ bt3,
    float* __restrict__ tokens) {
  const int pm = blockIdx.x;
  const int tid = threadIdx.x;
  __shared__ float xs[3][K];
  __shared__ float h1s[64 * K];
  __shared__ float h2s[128 * K];
  __shared__ float pms[2][EMB];

  const float* patch = patches + (size_t)pm * (K * 3);
  if (tid < 96) xs[tid % 3][tid / 3] = patch[tid];
  __syncthreads();

  const int cg = tid & 63;
  const int half = tid >> 6;
  const int pt0 = half * 16;
  const float rs = 1.0f / sqrtf(1.0f + 1e-5f);

  // L1: 3 -> 64
  {
    const int c = cg;
    const float w0 = W1[c], w1 = W1[64 + c], w2 = W1[128 + c];
    const float bb = b1[c];
    const float sc = g1[c] * rs, be = bt1[c];
    float o[16];
#pragma unroll
    for (int p = 0; p < 16; ++p) {
      int pt = pt0 + p;
      float a = xs[0][pt] * w0 + xs[1][pt] * w1 + xs[2][pt] * w2 + bb;
      o[p] = fmaxf(a * sc + be, 0.0f);
    }
    const int so = (c & 7) << 2;
#pragma unroll
    for (int p4 = 0; p4 < 16; p4 += 4) {
      *(float4*)&h1s[c * K + ((pt0 + p4) ^ so)] =
          make_float4(o[p4], o[p4 + 1], o[p4 + 2], o[p4 + 3]);
    }
  }
  __syncthreads();

  // L2: 64 -> 128, c-tile 2 x pt-tile 16
  {
    const int c = cg * 2;
    float acc0[16], acc1[16];
    const float bb0 = b2[c], bb1 = b2[c + 1];
#pragma unroll
    for (int p = 0; p < 16; ++p) { acc0[p] = bb0; acc1[p] = bb1; }
    for (int k = 0; k < 64; ++k) {
      const float2 w = *(const float2*)(W2 + k * 128 + c);
      const int so = (k & 7) << 2;
      float4 x0 = *(const float4*)&h1s[k * K + ((pt0 + 0) ^ so)];
      float4 x1 = *(const float4*)&h1s[k * K + ((pt0 + 4) ^ so)];
      float4 x2 = *(const float4*)&h1s[k * K + ((pt0 + 8) ^ so)];
      float4 x3 = *(const float4*)&h1s[k * K + ((pt0 + 12) ^ so)];
      float xv[16] = {x0.x, x0.y, x0.z, x0.w, x1.x, x1.y, x1.z, x1.w,
                      x2.x, x2.y, x2.z, x2.w, x3.x, x3.y, x3.z, x3.w};
#pragma unroll
      for (int p = 0; p < 16; ++p) {
        acc0[p] += xv[p] * w.x;
        acc1[p] += xv[p] * w.y;
      }
    }
    const float sc0 = g2[c] * rs, be0 = bt2[c];
    const float sc1 = g2[c + 1] * rs, be1 = bt2[c + 1];
    float o0[16], o1[16];
#pragma unroll
    for (int p = 0; p < 16; ++p) {
      o0[p] = fmaxf(acc0[p] * sc0 + be0, 0.0f);
      o1[p] = fmaxf(acc1[p] * sc1 + be1, 0.0f);
    }
    const int soa = (c & 7) << 2, sob = ((c + 1) & 7) << 2;
#pragma unroll
    for (int p4 = 0; p4 < 16; p4 += 4) {
      *(float4*)&h2s[c * K + ((pt0 + p4) ^ soa)] =
          make_float4(o0[p4], o0[p4 + 1], o0[p4 + 2], o0[p4 + 3]);
      *(float4*)&h2s[(c + 1) * K + ((pt0 + p4) ^ sob)] =
          make_float4(o1[p4], o1[p4 + 1], o1[p4 + 2], o1[p4 + 3]);
    }
  }
  __syncthreads();

  // L3: 128 -> 256, c-tile 4 x pt-tile 16, fused BN+ReLU+max over its pts
  {
    const int c = cg * 4;
    float acc[4][16];
#pragma unroll
    for (int i = 0; i < 4; ++i) {
      const float bb = b3[c + i];
#pragma unroll
      for (int p = 0; p < 16; ++p) acc[i][p] = bb;
    }
    for (int k = 0; k < 128; ++k) {
      const float4 w = *(const float4*)(W3 + (size_t)k * 256 + c);
      const int so = (k & 7) << 2;
      float4 x0 = *(const float4*)&h2s[k * K + ((pt0 + 0) ^ so)];
      float4 x1 = *(const float4*)&h2s[k * K + ((pt0 + 4) ^ so)];
      float4 x2 = *(const float4*)&h2s[k * K + ((pt0 + 8) ^ so)];
      float4 x3 = *(const float4*)&h2s[k * K + ((pt0 + 12) ^ so)];
      float xv[16] = {x0.x, x0.y, x0.z, x0.w, x1.x, x1.y, x1.z, x1.w,
                      x2.x, x2.y, x2.z, x2.w, x3.x, x3.y, x3.z, x3.w};
#pragma unroll
      for (int p = 0; p < 16; ++p) {
        acc[0][p] += xv[p] * w.x;
        acc[1][p] += xv[p] * w.y;
        acc[2][p] += xv[p] * w.z;
        acc[3][p] += xv[p] * w.w;
      }
    }
#pragma unroll
    for (int i = 0; i < 4; ++i) {
      const float sc = g3[c + i] * rs, be = bt3[c + i];
      float mx = 0.0f;  // ReLU outputs are >= 0, so 0 is a safe identity
#pragma unroll
      for (int p = 0; p < 16; ++p)
        mx = fmaxf(mx, fmaxf(acc[i][p] * sc + be, 0.0f));
      pms[half][c + i] = mx;
    }
  }
  __syncthreads();

  {
    const int c2 = tid * 2;
    float* to = tokens + (size_t)pm * EMB;
    to[c2] = fmaxf(pms[0][c2], pms[1][c2]);
    to[c2 + 1] = fmaxf(pms[0][c2 + 1], pms[1][c2 + 1]);
  }
}

// ------------------------------------------------------------- launcher ----
extern "C" void kernel_launch(void* const* d_in, const int* in_sizes, int n_in,
                              void* d_out, int out_size, void* d_ws,
                              size_t ws_size, hipStream_t stream) {
  const float* xyz = (const float*)d_in[0];
  const float* W1 = (const float*)d_in[1];
  const float* b1 = (const float*)d_in[2];
  const float* g1 = (const float*)d_in[3];
  const float* bt1 = (const float*)d_in[4];
  const float* W2 = (const float*)d_in[5];
  const float* b2 = (const float*)d_in[6];
  const float* g2 = (const float*)d_in[7];
  const float* bt2 = (const float*)d_in[8];
  const float* W3 = (const float*)d_in[9];
  const float* b3 = (const float*)d_in[10];
  const float* g3 = (const float*)d_in[11];
  const float* bt3 = (const float*)d_in[12];

  float* tokens = (float*)d_out;                       // (B,M,EMB)
  float* centers = tokens + (size_t)B * M * EMB;       // (B,M,3)
  float* patches = (float*)d_ws;                       // (B*M, K, 3)

  fps_kernel<<<B, FT, 0, stream>>>(xyz, centers);
  knn_kernel<<<B * M, KT, 0, stream>>>(xyz, centers, patches);
  mlp_kernel<<<B * M, MT, 0, stream>>>(patches, W1, b1, g1, bt1, W2, b2, g2,
                                       bt2, W3, b3, g3, bt3, tokens);
}

// Round 9
// 802.011 us; speedup vs baseline: 1.0760x; 1.0087x over previous
//
#include <hip/hip_runtime.h>

// Problem constants (fixed by setup_inputs)
constexpr int B   = 16;
constexpr int N   = 16384;
constexpr int M   = 256;   // n_centers
constexpr int K   = 32;    // knn
constexpr int EMB = 256;

// Exact (non-contracted) squared distance in the reference's association
// order: ((dx*dx + dy*dy) + dz*dz). Must be bit-identical to XLA CPU so the
// FPS argmax / kNN top-k selections match.
__device__ __forceinline__ float sqdist(float px, float py, float pz,
                                        float cx, float cy, float cz) {
  float dx = __fsub_rn(px, cx);
  float dy = __fsub_rn(py, cy);
  float dz = __fsub_rn(pz, cz);
  return __fadd_rn(__fadd_rn(__fmul_rn(dx, dx), __fmul_rn(dy, dy)),
                   __fmul_rn(dz, dz));
}

// ---------------------------------------------------------------- FPS ------
// 512 threads x 32 pts/thread. History: r5 (arrays, 1024thr) VGPR=48; r6
// (arrays, 512thr, lb(512,2)) VGPR=84; r7 (+asm pins) VGPR=84 — all spill
// the 128-float state to scratch: ~256KB/CU/iter of L1 reloads = ~5500
// cyc/iter, VALUBusy 3.6%. Diagnosis: launch_bounds' 2nd arg is only a MIN
// waves/EU (reg ceiling 256); the scheduler still targets max occupancy (6
// waves/SIMD @ 84 regs) and spills to get there. amdgpu_waves_per_eu(2,2)
// pins the occupancy target to exactly 2 waves/EU -> no incentive to shrink
// below 256 regs -> state stays register-resident.
constexpr int FT = 512;
constexpr int FP = N / FT;        // 32 points per thread
constexpr int FW = FT / 64;       // 8 waves
static_assert(FT == 512 && FP == 32, "macro expansion assumes 512x32");

#define FPS_REP(X) X(0) X(1) X(2) X(3) X(4) X(5) X(6) X(7) X(8) X(9) \
  X(10) X(11) X(12) X(13) X(14) X(15) X(16) X(17) X(18) X(19) \
  X(20) X(21) X(22) X(23) X(24) X(25) X(26) X(27) X(28) X(29) X(30) X(31)

__global__ __launch_bounds__(FT)
__attribute__((amdgpu_waves_per_eu(2, 2)))
void fps_kernel(const float* __restrict__ xyz, float* __restrict__ centers) {
  const int b = blockIdx.x;
  const int tid = threadIdx.x;
  const float* base = xyz + (size_t)b * N * 3;

#define FPS_DECL(i) float px##i, py##i, pz##i, ds##i;
  FPS_REP(FPS_DECL)
#undef FPS_DECL

#define FPS_LOAD(i) { const int n = tid + (i) * FT;      \
    px##i = base[n * 3 + 0];                              \
    py##i = base[n * 3 + 1];                              \
    pz##i = base[n * 3 + 2];                              \
    ds##i = __builtin_inff(); }
  FPS_REP(FPS_LOAD)
#undef FPS_LOAD

  // Pin coords in VGPRs: values become asm-defined -> the compiler can no
  // longer rematerialize the global loads inside the loop.
#define FPS_PIN(i) asm volatile("" : "+v"(px##i), "+v"(py##i), "+v"(pz##i));
  FPS_REP(FPS_PIN)
#undef FPS_PIN

  __shared__ float s_pv[2][FW];
  __shared__ int s_pn[2][FW];

  // deterministic start: carry = point 0
  float cx = base[0], cy = base[1], cz = base[2];

  for (int it = 0; it < M; ++it) {
    if (tid == 0) {  // emit current carry (matches lax.scan semantics)
      float* co = centers + ((size_t)b * M + it) * 3;
      co[0] = cx; co[1] = cy; co[2] = cz;
    }
    const int p = it & 1;

    // update running min-distances; track per-thread max (value, local j).
    // strict > : first (lowest j) wins ties; j is an inline-const cndmask.
    float bv = -1.0f;
    int bj = 0;
#define FPS_UPD(i) {                                       \
    float dx = __fsub_rn(px##i, cx);                       \
    float dy = __fsub_rn(py##i, cy);                       \
    float dz = __fsub_rn(pz##i, cz);                       \
    float dd = __fadd_rn(__fadd_rn(__fmul_rn(dx, dx),      \
                                   __fmul_rn(dy, dy)),     \
                         __fmul_rn(dz, dz));               \
    float nd = fminf(ds##i, dd);                           \
    ds##i = nd;                                            \
    bool g = nd > bv;                                      \
    bv = g ? nd : bv;                                      \
    bj = g ? (i) : bj; }
    FPS_REP(FPS_UPD)
#undef FPS_UPD
    int bn = (bj << 9) + tid;  // global point index (FT == 512)

    // wave-level argmax, tie -> lowest global index
#pragma unroll
    for (int mm = 32; mm >= 1; mm >>= 1) {
      float ov = __shfl_xor(bv, mm, 64);
      int on = __shfl_xor(bn, mm, 64);
      if (ov > bv || (ov == bv && on < bn)) { bv = ov; bn = on; }
    }
    if ((tid & 63) == 0) {
      s_pv[p][tid >> 6] = bv;
      s_pn[p][tid >> 6] = bn;
    }
    __syncthreads();

    // every thread reduces the 8 wave partials (broadcast LDS reads)
    float v = s_pv[p][0];
    int n = s_pn[p][0];
#pragma unroll
    for (int w = 1; w < FW; ++w) {
      float ov = s_pv[p][w];
      int on = s_pn[p][w];
      if (ov > v || (ov == v && on < n)) { v = ov; n = on; }
    }
    // broadcast-load next center (same address across the wave -> 1 fetch)
    cx = base[(size_t)n * 3 + 0];
    cy = base[(size_t)n * 3 + 1];
    cz = base[(size_t)n * 3 + 2];
    // no second barrier: double-buffered partials make it race-free
  }
}

// ---------------------------------------------------------------- kNN ------
// Bucket-select on float bit prefixes (monotone for d >= 0). Only the SET of
// 32 nearest matters (max-pool later), so slots are written in arbitrary
// order; boundary-bucket ties resolved exactly by (bits, index).
constexpr int KT = 256;
constexpr int CAP = 512;
constexpr int NBUCKET = 1024;

__global__ __launch_bounds__(KT) void knn_kernel(
    const float* __restrict__ xyz, const float* __restrict__ centers,
    float* __restrict__ patches) {
  const int blk = blockIdx.x;      // b*M + m
  const int b = blk >> 8;          // M == 256
  const int tid = threadIdx.x;
  const float* base = xyz + (size_t)b * N * 3;

  __shared__ int hist[NBUCKET];
  __shared__ unsigned cb[CAP];
  __shared__ int ci[CAP];
  __shared__ int s_nin, s_ncand, s_tb;
  __shared__ int s_wsum[KT / 64];
  __shared__ float s_cc[3];

  if (tid == 0) {
    const float* c = centers + (size_t)blk * 3;
    s_cc[0] = c[0]; s_cc[1] = c[1]; s_cc[2] = c[2];
    s_nin = 0; s_ncand = 0;
  }
  for (int i = tid; i < NBUCKET; i += KT) hist[i] = 0;
  __syncthreads();

  const float cx = s_cc[0], cy = s_cc[1], cz = s_cc[2];

  // pass 1: histogram of 10-bit float prefixes
  for (int n = tid; n < N; n += KT) {
    float d = sqdist(base[n * 3], base[n * 3 + 1], base[n * 3 + 2], cx, cy, cz);
    atomicAdd(&hist[__float_as_uint(d) >> 21], 1);
  }
  __syncthreads();

  // block scan over 1024 buckets (4 per thread) to find threshold bucket
  int h0[4];
  int loc = 0;
#pragma unroll
  for (int i = 0; i < 4; ++i) { h0[i] = hist[tid * 4 + i]; loc += h0[i]; }
  int lane = tid & 63, wid = tid >> 6;
  int scan = loc;
  for (int off = 1; off < 64; off <<= 1) {
    int o = __shfl_up(scan, off, 64);
    if (lane >= off) scan += o;
  }
  if (lane == 63) s_wsum[wid] = scan;
  __syncthreads();
  int woff = 0;
  for (int w = 0; w < wid; ++w) woff += s_wsum[w];
  int c0 = woff + scan - loc;  // count strictly below this thread's buckets
#pragma unroll
  for (int i = 0; i < 4; ++i) {
    int c1 = c0 + h0[i];
    if (c0 < K && c1 >= K) s_tb = tid * 4 + i;  // unique crossing bucket
    c0 = c1;
  }
  __syncthreads();
  const int tb = s_tb;
  const unsigned lo = (unsigned)tb << 21;
  const unsigned hi = (unsigned)(tb + 1) << 21;

  // pass 2: emit sure-ins, collect boundary candidates
  for (int n = tid; n < N; n += KT) {
    float x = base[n * 3], y = base[n * 3 + 1], z = base[n * 3 + 2];
    float d = sqdist(x, y, z, cx, cy, cz);
    unsigned bits = __float_as_uint(d);
    if (bits < lo) {
      int pos = atomicAdd(&s_nin, 1);
      float* p = patches + ((size_t)blk * K + pos) * 3;
      p[0] = __fsub_rn(x, cx); p[1] = __fsub_rn(y, cy); p[2] = __fsub_rn(z, cz);
    } else if (bits < hi) {
      int q = atomicAdd(&s_ncand, 1);
      if (q < CAP) { cb[q] = bits; ci[q] = n; }
    }
  }
  __syncthreads();

  // exact rank-select among boundary candidates: (bits, idx) lexicographic
  const int nin = s_nin;
  const int ncand = min(s_ncand, CAP);
  const int nsel = K - nin;
  for (int j = tid; j < ncand; j += KT) {
    unsigned bj = cb[j];
    int ij = ci[j];
    int rank = 0;
    for (int i2 = 0; i2 < ncand; ++i2) {
      unsigned bv = cb[i2];
      int iv = ci[i2];
      rank += (bv < bj || (bv == bj && iv < ij)) ? 1 : 0;
    }
    if (rank < nsel) {
      float x = base[ij * 3], y = base[ij * 3 + 1], z = base[ij * 3 + 2];
      float* p = patches + ((size_t)blk * K + nin + rank) * 3;
      p[0] = __fsub_rn(x, cx); p[1] = __fsub_rn(y, cy); p[2] = __fsub_rn(z, cz);
    }
  }
}

// ---------------------------------------------------------------- MLP ------
// One block per patch. h1/h2 staged in LDS, rows XOR-swizzled so the b128
// writes are conflict-light; reads are uniform-address broadcasts.
constexpr int MT = 128;

__global__ __launch_bounds__(MT) void mlp_kernel(
    const float* __restrict__ patches,
    const float* __restrict__ W1, const float* __restrict__ b1,
    const float* __restrict__ g1, const float* __restrict__ bt1,
    const float* __restrict__ W2, const float* __restrict__ b2,
    const float* __restrict__ g2, const float* __restrict__ bt2,
    const float* __restrict__ W3, const float* __restrict__ b3,
    const float* __restrict__ g3, const float* __restrict__ bt3,
    float* __restrict__ tokens) {
  const int pm = blockIdx.x;
  const int tid = threadIdx.x;
  __shared__ float xs[3][K];
  __shared__ float h1s[64 * K];
  __shared__ float h2s[128 * K];
  __shared__ float pms[2][EMB];

  const float* patch = patches + (size_t)pm * (K * 3);
  if (tid < 96) xs[tid % 3][tid / 3] = patch[tid];
  __syncthreads();

  const int cg = tid & 63;
  const int half = tid >> 6;
  const int pt0 = half * 16;
  const float rs = 1.0f / sqrtf(1.0f + 1e-5f);

  // L1: 3 -> 64
  {
    const int c = cg;
    const float w0 = W1[c], w1 = W1[64 + c], w2 = W1[128 + c];
    const float bb = b1[c];
    const float sc = g1[c] * rs, be = bt1[c];
    float o[16];
#pragma unroll
    for (int p = 0; p < 16; ++p) {
      int pt = pt0 + p;
      float a = xs[0][pt] * w0 + xs[1][pt] * w1 + xs[2][pt] * w2 + bb;
      o[p] = fmaxf(a * sc + be, 0.0f);
    }
    const int so = (c & 7) << 2;
#pragma unroll
    for (int p4 = 0; p4 < 16; p4 += 4) {
      *(float4*)&h1s[c * K + ((pt0 + p4) ^ so)] =
          make_float4(o[p4], o[p4 + 1], o[p4 + 2], o[p4 + 3]);
    }
  }
  __syncthreads();

  // L2: 64 -> 128, c-tile 2 x pt-tile 16
  {
    const int c = cg * 2;
    float acc0[16], acc1[16];
    const float bb0 = b2[c], bb1 = b2[c + 1];
#pragma unroll
    for (int p = 0; p < 16; ++p) { acc0[p] = bb0; acc1[p] = bb1; }
    for (int k = 0; k < 64; ++k) {
      const float2 w = *(const float2*)(W2 + k * 128 + c);
      const int so = (k & 7) << 2;
      float4 x0 = *(const float4*)&h1s[k * K + ((pt0 + 0) ^ so)];
      float4 x1 = *(const float4*)&h1s[k * K + ((pt0 + 4) ^ so)];
      float4 x2 = *(const float4*)&h1s[k * K + ((pt0 + 8) ^ so)];
      float4 x3 = *(const float4*)&h1s[k * K + ((pt0 + 12) ^ so)];
      float xv[16] = {x0.x, x0.y, x0.z, x0.w, x1.x, x1.y, x1.z, x1.w,
                      x2.x, x2.y, x2.z, x2.w, x3.x, x3.y, x3.z, x3.w};
#pragma unroll
      for (int p = 0; p < 16; ++p) {
        acc0[p] += xv[p] * w.x;
        acc1[p] += xv[p] * w.y;
      }
    }
    const float sc0 = g2[c] * rs, be0 = bt2[c];
    const float sc1 = g2[c + 1] * rs, be1 = bt2[c + 1];
    float o0[16], o1[16];
#pragma unroll
    for (int p = 0; p < 16; ++p) {
      o0[p] = fmaxf(acc0[p] * sc0 + be0, 0.0f);
      o1[p] = fmaxf(acc1[p] * sc1 + be1, 0.0f);
    }
    const int soa = (c & 7) << 2, sob = ((c + 1) & 7) << 2;
#pragma unroll
    for (int p4 = 0; p4 < 16; p4 += 4) {
      *(float4*)&h2s[c * K + ((pt0 + p4) ^ soa)] =
          make_float4(o0[p4], o0[p4 + 1], o0[p4 + 2], o0[p4 + 3]);
      *(float4*)&h2s[(c + 1) * K + ((pt0 + p4) ^ sob)] =
          make_float4(o1[p4], o1[p4 + 1], o1[p4 + 2], o1[p4 + 3]);
    }
  }
  __syncthreads();

  // L3: 128 -> 256, c-tile 4 x pt-tile 16, fused BN+ReLU+max over its pts
  {
    const int c = cg * 4;
    float acc[4][16];
#pragma unroll
    for (int i = 0; i < 4; ++i) {
      const float bb = b3[c + i];
#pragma unroll
      for (int p = 0; p < 16; ++p) acc[i][p] = bb;
    }
    for (int k = 0; k < 128; ++k) {
      const float4 w = *(const float4*)(W3 + (size_t)k * 256 + c);
      const int so = (k & 7) << 2;
      float4 x0 = *(const float4*)&h2s[k * K + ((pt0 + 0) ^ so)];
      float4 x1 = *(const float4*)&h2s[k * K + ((pt0 + 4) ^ so)];
      float4 x2 = *(const float4*)&h2s[k * K + ((pt0 + 8) ^ so)];
      float4 x3 = *(const float4*)&h2s[k * K + ((pt0 + 12) ^ so)];
      float xv[16] = {x0.x, x0.y, x0.z, x0.w, x1.x, x1.y, x1.z, x1.w,
                      x2.x, x2.y, x2.z, x2.w, x3.x, x3.y, x3.z, x3.w};
#pragma unroll
      for (int p = 0; p < 16; ++p) {
        acc[0][p] += xv[p] * w.x;
        acc[1][p] += xv[p] * w.y;
        acc[2][p] += xv[p] * w.z;
        acc[3][p] += xv[p] * w.w;
      }
    }
#pragma unroll
    for (int i = 0; i < 4; ++i) {
      const float sc = g3[c + i] * rs, be = bt3[c + i];
      float mx = 0.0f;  // ReLU outputs are >= 0, so 0 is a safe identity
#pragma unroll
      for (int p = 0; p < 16; ++p)
        mx = fmaxf(mx, fmaxf(acc[i][p] * sc + be, 0.0f));
      pms[half][c + i] = mx;
    }
  }
  __syncthreads();

  {
    const int c2 = tid * 2;
    float* to = tokens + (size_t)pm * EMB;
    to[c2] = fmaxf(pms[0][c2], pms[1][c2]);
    to[c2 + 1] = fmaxf(pms[0][c2 + 1], pms[1][c2 + 1]);
  }
}

// ------------------------------------------------------------- launcher ----
extern "C" void kernel_launch(void* const* d_in, const int* in_sizes, int n_in,
                              void* d_out, int out_size, void* d_ws,
                              size_t ws_size, hipStream_t stream) {
  const float* xyz = (const float*)d_in[0];
  const float* W1 = (const float*)d_in[1];
  const float* b1 = (const float*)d_in[2];
  const float* g1 = (const float*)d_in[3];
  const float* bt1 = (const float*)d_in[4];
  const float* W2 = (const float*)d_in[5];
  const float* b2 = (const float*)d_in[6];
  const float* g2 = (const float*)d_in[7];
  const float* bt2 = (const float*)d_in[8];
  const float* W3 = (const float*)d_in[9];
  const float* b3 = (const float*)d_in[10];
  const float* g3 = (const float*)d_in[11];
  const float* bt3 = (const float*)d_in[12];

  float* tokens = (float*)d_out;                       // (B,M,EMB)
  float* centers = tokens + (size_t)B * M * EMB;       // (B,M,3)
  float* patches = (float*)d_ws;                       // (B*M, K, 3)

  fps_kernel<<<B, FT, 0, stream>>>(xyz, centers);
  knn_kernel<<<B * M, KT, 0, stream>>>(xyz, centers, patches);
  mlp_kernel<<<B * M, MT, 0, stream>>>(patches, W1, b1, g1, bt1, W2, b2, g2,
                                       bt2, W3, b3, g3, bt3, tokens);
}